// Round 6
// baseline (402.385 us; speedup 1.0000x reference)
//
#include <hip/hip_runtime.h>
#include <math.h>

#define B_ 8
#define C_ 256
#define N_ 2048

typedef __attribute__((ext_vector_type(8))) short bf16x8;
typedef __attribute__((ext_vector_type(4))) float f32x4;
typedef unsigned int u32;
typedef unsigned short u16;

#define MFMA(a, b, c) __builtin_amdgcn_mfma_f32_16x16x32_bf16(a, b, c, 0, 0, 0)

__device__ __forceinline__ u16 f2bf(float f) {            // RNE float->bf16
    u32 u = __float_as_uint(f);
    return (u16)((u + 0x7FFFu + ((u >> 16) & 1u)) >> 16);
}
__device__ __forceinline__ bf16x8 ldg8(const u16* p) {
    return *reinterpret_cast<const bf16x8*>(p);
}

// ---------------------------------------------------------------------------
// Kernel 1: fused QKV projection -> bf16 planes. (unchanged from round 5)
//   Qt : [B][N][C] bf16 (pre-scaled by 1/16),  Kt : [B][N][C],  V : [B][C][N]
// ---------------------------------------------------------------------------
__global__ __launch_bounds__(256) void qkv_k(
    const float* __restrict__ x,
    const float* __restrict__ Wq, const float* __restrict__ bq,
    const float* __restrict__ Wk, const float* __restrict__ bk,
    const float* __restrict__ Wv, const float* __restrict__ bv,
    u16* __restrict__ qtp, u16* __restrict__ ktp, u16* __restrict__ vtp)
{
    const int b   = blockIdx.z;
    const int o0  = blockIdx.y * 64;
    const int n0  = blockIdx.x * 64;
    const int tid = threadIdx.x;
    const int tx  = tid & 15;
    const int ty  = tid >> 4;

    __shared__ float xs[16][68];
    __shared__ float wqs[16][68], wks[16][68], wvs[16][68];
    __shared__ float tb[64][68];            // transpose staging

    float aq[4][4] = {}, ak[4][4] = {}, av[4][4] = {};

    const float* xb = x + (size_t)b * C_ * N_;
    const int xr = tid >> 4, xc = (tid & 15) * 4;
    const int wr = tid >> 2, wc = (tid & 3) * 4;

    for (int k0 = 0; k0 < C_; k0 += 16) {
        float4 xv = *(const float4*)(xb + (size_t)(k0 + xr) * N_ + n0 + xc);
        float4 q4 = *(const float4*)(Wq + (size_t)(o0 + wr) * C_ + k0 + wc);
        float4 k4 = *(const float4*)(Wk + (size_t)(o0 + wr) * C_ + k0 + wc);
        float4 v4 = *(const float4*)(Wv + (size_t)(o0 + wr) * C_ + k0 + wc);
        __syncthreads();   // previous iteration's LDS reads done
        *(float4*)&xs[xr][xc] = xv;
        wqs[wc+0][wr] = q4.x; wqs[wc+1][wr] = q4.y; wqs[wc+2][wr] = q4.z; wqs[wc+3][wr] = q4.w;
        wks[wc+0][wr] = k4.x; wks[wc+1][wr] = k4.y; wks[wc+2][wr] = k4.z; wks[wc+3][wr] = k4.w;
        wvs[wc+0][wr] = v4.x; wvs[wc+1][wr] = v4.y; wvs[wc+2][wr] = v4.z; wvs[wc+3][wr] = v4.w;
        __syncthreads();

        #pragma unroll
        for (int k = 0; k < 16; ++k) {
            float xl[4], ql_[4], kl_[4], vl_[4];
            *(float4*)xl  = *(const float4*)&xs[k][tx*4];
            *(float4*)ql_ = *(const float4*)&wqs[k][ty*4];
            *(float4*)kl_ = *(const float4*)&wks[k][ty*4];
            *(float4*)vl_ = *(const float4*)&wvs[k][ty*4];
            #pragma unroll
            for (int i = 0; i < 4; ++i)
                #pragma unroll
                for (int j = 0; j < 4; ++j) {
                    aq[i][j] += ql_[i] * xl[j];
                    ak[i][j] += kl_[i] * xl[j];
                    av[i][j] += vl_[i] * xl[j];
                }
        }
    }

    // ---- V: bf16 store, [B][C][N] ----
    #pragma unroll
    for (int i = 0; i < 4; ++i) {
        const int o = o0 + ty*4 + i;
        const float bvv = bv[o];
        const size_t base = ((size_t)b * C_ + o) * N_ + n0 + tx*4;
        u16 h[4];
        #pragma unroll
        for (int j = 0; j < 4; ++j) h[j] = f2bf(av[i][j] + bvv);
        uint2 hv;
        hv.x = (u32)h[0] | ((u32)h[1] << 16);
        hv.y = (u32)h[2] | ((u32)h[3] << 16);
        *reinterpret_cast<uint2*>(vtp + base) = hv;
    }

    // ---- Q: transpose to [B][N][C], pre-scaled by 1/16 ----
    __syncthreads();
    #pragma unroll
    for (int i = 0; i < 4; ++i) {
        const float bqv = bq[o0 + ty*4 + i];
        #pragma unroll
        for (int j = 0; j < 4; ++j)
            tb[tx*4 + j][ty*4 + i] = (aq[i][j] + bqv) * 0.0625f;
    }
    __syncthreads();
    {
        const int r = tid >> 2, och = (tid & 3) * 16;
        float vals[16];
        #pragma unroll
        for (int u = 0; u < 4; ++u)
            *(float4*)&vals[u*4] = *(const float4*)&tb[r][och + u*4];
        u32 hw[8];
        #pragma unroll
        for (int e = 0; e < 8; ++e)
            hw[e] = (u32)f2bf(vals[2*e]) | ((u32)f2bf(vals[2*e+1]) << 16);
        const size_t qb = ((size_t)b * N_ + n0 + r) * C_ + o0 + och;
        reinterpret_cast<uint4*>(qtp + qb)[0] = make_uint4(hw[0], hw[1], hw[2], hw[3]);
        reinterpret_cast<uint4*>(qtp + qb)[1] = make_uint4(hw[4], hw[5], hw[6], hw[7]);
    }

    // ---- K: transpose to [B][N][C] ----
    __syncthreads();
    #pragma unroll
    for (int i = 0; i < 4; ++i) {
        const float bkv = bk[o0 + ty*4 + i];
        #pragma unroll
        for (int j = 0; j < 4; ++j)
            tb[tx*4 + j][ty*4 + i] = ak[i][j] + bkv;
    }
    __syncthreads();
    {
        const int r = tid >> 2, och = (tid & 3) * 16;
        float vals[16];
        #pragma unroll
        for (int u = 0; u < 4; ++u)
            *(float4*)&vals[u*4] = *(const float4*)&tb[r][och + u*4];
        u32 hw[8];
        #pragma unroll
        for (int e = 0; e < 8; ++e)
            hw[e] = (u32)f2bf(vals[2*e]) | ((u32)f2bf(vals[2*e+1]) << 16);
        const size_t kb2 = ((size_t)b * N_ + n0 + r) * C_ + o0 + och;
        reinterpret_cast<uint4*>(ktp + kb2)[0] = make_uint4(hw[0], hw[1], hw[2], hw[3]);
        reinterpret_cast<uint4*>(ktp + kb2)[1] = make_uint4(hw[4], hw[5], hw[6], hw[7]);
    }
}

// ---------------------------------------------------------------------------
// Kernel 2: MFMA flash attention (swapped QK^T), split-KV across 4 waves.
// SAME math as round 5. Change: the 69.6 KB whole-C merge buffer is replaced
// by a 17.4 KB 64-channel chunk buffer, merged in 4 barrier-separated passes.
// LDS 79.4 KB -> ~27 KB: occupancy becomes register-bound (~3 waves/SIMD)
// instead of LDS-bound (2 blocks/CU).
// ---------------------------------------------------------------------------
__global__ __launch_bounds__(256) void attn_k(
    const u16* __restrict__ qt, const u16* __restrict__ kt,
    const u16* __restrict__ vt, const float* __restrict__ xres,
    float* __restrict__ out)
{
    const int gid = blockIdx.x;
    const int b   = gid & 7;
    const int n0  = (gid >> 3) * 16;
    const int tid = threadIdx.x;
    const int w   = tid >> 6;
    const int l   = tid & 63;
    const int lx  = l & 15;
    const int lg  = l >> 4;

    __shared__ u32   pbuf[4][32][17];        //  8704 B  (P as bf16 in low 16b)
    __shared__ float mchunk[4][64][17];      // 17408 B  (64-channel merge chunk)
    __shared__ float mlbuf[4][2][16];        //   512 B
    __shared__ float wbuf[4][16];            //   256 B

    // Q fragments (B-operand): lane holds Q[n0+lx][k = kb*32 + lg*8 + e]
    const u16* qrow = qt + ((size_t)b * N_ + n0 + lx) * C_ + lg * 8;
    bf16x8 qf[8];
    #pragma unroll
    for (int kb = 0; kb < 8; ++kb) qf[kb] = ldg8(qrow + kb * 32);

    const u16* krow = kt + ((size_t)b * N_ + lx) * C_ + lg * 8;
    const u16* vrow = vt + ((size_t)b * C_ + lx) * N_ + lg * 8;

    f32x4 acc[16];
    #pragma unroll
    for (int ct = 0; ct < 16; ++ct) acc[ct] = (f32x4){0.f, 0.f, 0.f, 0.f};
    float mrun = -1e30f, lrun = 0.f;   // row n = lx (replicated over 4 lanes)

    #pragma unroll 1
    for (int it = 0; it < 16; ++it) {
        const int m0 = (it * 4 + w) * 32;

        // ---- S^T chunk: A = K rows (m), B = Q rows (n) ----
        f32x4 s0 = (f32x4){0.f,0.f,0.f,0.f}, s1 = (f32x4){0.f,0.f,0.f,0.f};
        const u16* k0 = krow + (size_t)m0 * C_;
        #pragma unroll
        for (int kb = 0; kb < 8; ++kb) {
            bf16x8 a0 = ldg8(k0 + kb * 32);            // K row m0+lx
            bf16x8 a1 = ldg8(k0 + 16 * C_ + kb * 32);  // K row m0+16+lx
            s0 = MFMA(a0, qf[kb], s0);
            s1 = MFMA(a1, qf[kb], s1);
        }

        // ---- online softmax, row n = lx (lane-local state) ----
        float mx = fmaxf(fmaxf(fmaxf(s0[0], s0[1]), fmaxf(s0[2], s0[3])),
                         fmaxf(fmaxf(s1[0], s1[1]), fmaxf(s1[2], s1[3])));
        mx = fmaxf(mx, __shfl_xor(mx, 16));
        mx = fmaxf(mx, __shfl_xor(mx, 32));
        const float mnew  = fmaxf(mrun, mx);
        const float alpha = __expf(mrun - mnew);
        float p0[4], p1[4], r = 0.f;
        #pragma unroll
        for (int j = 0; j < 4; ++j) {
            p0[j] = __expf(s0[j] - mnew);
            p1[j] = __expf(s1[j] - mnew);
            r += p0[j] + p1[j];
        }
        r += __shfl_xor(r, 16);
        r += __shfl_xor(r, 32);
        lrun = lrun * alpha + r;
        mrun = mnew;

        // rescale acc by own alpha (acc col n == lx == alpha's row)
        if (__any(alpha != 1.0f)) {
            #pragma unroll
            for (int ct = 0; ct < 16; ++ct) {
                acc[ct][0] *= alpha; acc[ct][1] *= alpha;
                acc[ct][2] *= alpha; acc[ct][3] *= alpha;
            }
        }

        // ---- P exchange: pbuf[w][m-slot][n] (bf16 in low 16 bits) ----
        #pragma unroll
        for (int j = 0; j < 4; ++j) {
            pbuf[w][4*lg + j][lx]      = (u32)f2bf(p0[j]);
            pbuf[w][16 + 4*lg + j][lx] = (u32)f2bf(p1[j]);
        }
        bf16x8 pf;   // B-operand: lane l elem e = P[m-slot lg*8+e][n=lx]
        #pragma unroll
        for (int e = 0; e < 8; ++e)
            pf[e] = (short)(u16)pbuf[w][lg*8 + e][lx];

        // ---- PV: acc[ct] += V[c = 16ct+row][m-chunk] x P ----
        const u16* v0 = vrow + m0;
        #pragma unroll
        for (int ct = 0; ct < 16; ++ct) {
            bf16x8 ah = ldg8(v0 + (size_t)ct * 16 * N_);
            acc[ct] = MFMA(ah, pf, acc[ct]);
        }
    }

    // ---- split-KV merge weights ----
    if (lg == 0) {                       // lanes 0..15: row lx
        mlbuf[w][0][lx] = mrun;
        mlbuf[w][1][lx] = lrun;
    }
    __syncthreads();
    if (tid < 16) {
        const int xi = tid;
        const float m0_ = mlbuf[0][0][xi], m1_ = mlbuf[1][0][xi];
        const float m2_ = mlbuf[2][0][xi], m3_ = mlbuf[3][0][xi];
        const float M = fmaxf(fmaxf(m0_, m1_), fmaxf(m2_, m3_));
        const float e0 = __expf(m0_ - M), e1 = __expf(m1_ - M);
        const float e2 = __expf(m2_ - M), e3 = __expf(m3_ - M);
        const float denom = e0 * mlbuf[0][1][xi] + e1 * mlbuf[1][1][xi]
                          + e2 * mlbuf[2][1][xi] + e3 * mlbuf[3][1][xi];
        const float inv = 1.0f / denom;
        wbuf[0][xi] = e0 * inv; wbuf[1][xi] = e1 * inv;
        wbuf[2][xi] = e2 * inv; wbuf[3][xi] = e3 * inv;
    }
    __syncthreads();

    // ---- chunked merge + residual + store: 4 passes of 64 channels ----
    const int cl = tid >> 2;             // 0..63  (channel within chunk)
    const int nq = (tid & 3) * 4;        // 0,4,8,12 (n quad)
    #pragma unroll 1
    for (int g = 0; g < 4; ++g) {
        #pragma unroll
        for (int q = 0; q < 4; ++q) {    // ct = 4g+q -> c_local = 16q+4lg+j
            #pragma unroll
            for (int j = 0; j < 4; ++j)
                mchunk[w][16*q + 4*lg + j][lx] = acc[4*g + q][j];
        }
        __syncthreads();
        {
            const size_t gidx = ((size_t)b * C_ + g*64 + cl) * N_ + n0 + nq;
            float4 res = *(const float4*)(xres + gidx);
            float4 o;
            #pragma unroll
            for (int j = 0; j < 4; ++j) {
                const int xi = nq + j;
                const float v = wbuf[0][xi] * mchunk[0][cl][xi]
                              + wbuf[1][xi] * mchunk[1][cl][xi]
                              + wbuf[2][xi] * mchunk[2][cl][xi]
                              + wbuf[3][xi] * mchunk[3][cl][xi];
                (&o.x)[j] = v + (&res.x)[j];
            }
            *(float4*)(out + gidx) = o;
        }
        __syncthreads();                 // mchunk reused next pass
    }
}

// ---------------------------------------------------------------------------
extern "C" void kernel_launch(void* const* d_in, const int* in_sizes, int n_in,
                              void* d_out, int out_size, void* d_ws, size_t ws_size,
                              hipStream_t stream) {
    const float* x  = (const float*)d_in[0];
    const float* Wq = (const float*)d_in[1];
    const float* bq = (const float*)d_in[2];
    const float* Wk = (const float*)d_in[3];
    const float* bk = (const float*)d_in[4];
    const float* Wv = (const float*)d_in[5];
    const float* bv = (const float*)d_in[6];
    float* outp = (float*)d_out;

    const size_t plane = (size_t)B_ * C_ * N_;   // 4,194,304 elements
    u16* qt = (u16*)d_ws;        // [B][N][C] bf16, pre-scaled 1/16
    u16* kt = qt + plane;        // [B][N][C]
    u16* vt = kt + plane;        // [B][C][N]  -> total 3*plane*2 = 25,165,824 B

    dim3 g1(N_/64, C_/64, B_);
    qkv_k<<<g1, 256, 0, stream>>>(x, Wq, bq, Wk, bk, Wv, bv, qt, kt, vt);

    attn_k<<<1024, 256, 0, stream>>>(qt, kt, vt, x, outp);
}

// Round 9
// 383.151 us; speedup vs baseline: 1.0502x; 1.0502x over previous
//
#include <hip/hip_runtime.h>
#include <math.h>

#define B_ 8
#define C_ 256
#define N_ 2048

typedef __attribute__((ext_vector_type(8))) short bf16x8;
typedef __attribute__((ext_vector_type(4))) float f32x4;
typedef unsigned int u32;
typedef unsigned short u16;

#define MFMA(a, b, c) __builtin_amdgcn_mfma_f32_16x16x32_bf16(a, b, c, 0, 0, 0)

__device__ __forceinline__ u16 f2bf(float f) {            // RNE float->bf16
    u32 u = __float_as_uint(f);
    return (u16)((u + 0x7FFFu + ((u >> 16) & 1u)) >> 16);
}
__device__ __forceinline__ bf16x8 ldg8(const u16* p) {
    return *reinterpret_cast<const bf16x8*>(p);
}

// ---------------------------------------------------------------------------
// Kernel 1: fused QKV projection -> bf16 planes. (unchanged — working)
//   Qt : [B][N][C] bf16 (pre-scaled by 1/16),  Kt : [B][N][C],  V : [B][C][N]
// ---------------------------------------------------------------------------
__global__ __launch_bounds__(256) void qkv_k(
    const float* __restrict__ x,
    const float* __restrict__ Wq, const float* __restrict__ bq,
    const float* __restrict__ Wk, const float* __restrict__ bk,
    const float* __restrict__ Wv, const float* __restrict__ bv,
    u16* __restrict__ qtp, u16* __restrict__ ktp, u16* __restrict__ vtp)
{
    const int b   = blockIdx.z;
    const int o0  = blockIdx.y * 64;
    const int n0  = blockIdx.x * 64;
    const int tid = threadIdx.x;
    const int tx  = tid & 15;
    const int ty  = tid >> 4;

    __shared__ float xs[16][68];
    __shared__ float wqs[16][68], wks[16][68], wvs[16][68];
    __shared__ float tb[64][68];            // transpose staging

    float aq[4][4] = {}, ak[4][4] = {}, av[4][4] = {};

    const float* xb = x + (size_t)b * C_ * N_;
    const int xr = tid >> 4, xc = (tid & 15) * 4;
    const int wr = tid >> 2, wc = (tid & 3) * 4;

    for (int k0 = 0; k0 < C_; k0 += 16) {
        float4 xv = *(const float4*)(xb + (size_t)(k0 + xr) * N_ + n0 + xc);
        float4 q4 = *(const float4*)(Wq + (size_t)(o0 + wr) * C_ + k0 + wc);
        float4 k4 = *(const float4*)(Wk + (size_t)(o0 + wr) * C_ + k0 + wc);
        float4 v4 = *(const float4*)(Wv + (size_t)(o0 + wr) * C_ + k0 + wc);
        __syncthreads();   // previous iteration's LDS reads done
        *(float4*)&xs[xr][xc] = xv;
        wqs[wc+0][wr] = q4.x; wqs[wc+1][wr] = q4.y; wqs[wc+2][wr] = q4.z; wqs[wc+3][wr] = q4.w;
        wks[wc+0][wr] = k4.x; wks[wc+1][wr] = k4.y; wks[wc+2][wr] = k4.z; wks[wc+3][wr] = k4.w;
        wvs[wc+0][wr] = v4.x; wvs[wc+1][wr] = v4.y; wvs[wc+2][wr] = v4.z; wvs[wc+3][wr] = v4.w;
        __syncthreads();

        #pragma unroll
        for (int k = 0; k < 16; ++k) {
            float xl[4], ql_[4], kl_[4], vl_[4];
            *(float4*)xl  = *(const float4*)&xs[k][tx*4];
            *(float4*)ql_ = *(const float4*)&wqs[k][ty*4];
            *(float4*)kl_ = *(const float4*)&wks[k][ty*4];
            *(float4*)vl_ = *(const float4*)&wvs[k][ty*4];
            #pragma unroll
            for (int i = 0; i < 4; ++i)
                #pragma unroll
                for (int j = 0; j < 4; ++j) {
                    aq[i][j] += ql_[i] * xl[j];
                    ak[i][j] += kl_[i] * xl[j];
                    av[i][j] += vl_[i] * xl[j];
                }
        }
    }

    // ---- V: bf16 store, [B][C][N] ----
    #pragma unroll
    for (int i = 0; i < 4; ++i) {
        const int o = o0 + ty*4 + i;
        const float bvv = bv[o];
        const size_t base = ((size_t)b * C_ + o) * N_ + n0 + tx*4;
        u16 h[4];
        #pragma unroll
        for (int j = 0; j < 4; ++j) h[j] = f2bf(av[i][j] + bvv);
        uint2 hv;
        hv.x = (u32)h[0] | ((u32)h[1] << 16);
        hv.y = (u32)h[2] | ((u32)h[3] << 16);
        *reinterpret_cast<uint2*>(vtp + base) = hv;
    }

    // ---- Q: transpose to [B][N][C], pre-scaled by 1/16 ----
    __syncthreads();
    #pragma unroll
    for (int i = 0; i < 4; ++i) {
        const float bqv = bq[o0 + ty*4 + i];
        #pragma unroll
        for (int j = 0; j < 4; ++j)
            tb[tx*4 + j][ty*4 + i] = (aq[i][j] + bqv) * 0.0625f;
    }
    __syncthreads();
    {
        const int r = tid >> 2, och = (tid & 3) * 16;
        float vals[16];
        #pragma unroll
        for (int u = 0; u < 4; ++u)
            *(float4*)&vals[u*4] = *(const float4*)&tb[r][och + u*4];
        u32 hw[8];
        #pragma unroll
        for (int e = 0; e < 8; ++e)
            hw[e] = (u32)f2bf(vals[2*e]) | ((u32)f2bf(vals[2*e+1]) << 16);
        const size_t qb = ((size_t)b * N_ + n0 + r) * C_ + o0 + och;
        reinterpret_cast<uint4*>(qtp + qb)[0] = make_uint4(hw[0], hw[1], hw[2], hw[3]);
        reinterpret_cast<uint4*>(qtp + qb)[1] = make_uint4(hw[4], hw[5], hw[6], hw[7]);
    }

    // ---- K: transpose to [B][N][C] ----
    __syncthreads();
    #pragma unroll
    for (int i = 0; i < 4; ++i) {
        const float bkv = bk[o0 + ty*4 + i];
        #pragma unroll
        for (int j = 0; j < 4; ++j)
            tb[tx*4 + j][ty*4 + i] = ak[i][j] + bkv;
    }
    __syncthreads();
    {
        const int r = tid >> 2, och = (tid & 3) * 16;
        float vals[16];
        #pragma unroll
        for (int u = 0; u < 4; ++u)
            *(float4*)&vals[u*4] = *(const float4*)&tb[r][och + u*4];
        u32 hw[8];
        #pragma unroll
        for (int e = 0; e < 8; ++e)
            hw[e] = (u32)f2bf(vals[2*e]) | ((u32)f2bf(vals[2*e+1]) << 16);
        const size_t kb2 = ((size_t)b * N_ + n0 + r) * C_ + o0 + och;
        reinterpret_cast<uint4*>(ktp + kb2)[0] = make_uint4(hw[0], hw[1], hw[2], hw[3]);
        reinterpret_cast<uint4*>(ktp + kb2)[1] = make_uint4(hw[4], hw[5], hw[6], hw[7]);
    }
}

// ---------------------------------------------------------------------------
// Kernel 2: MFMA flash attention — CHANNEL-SPLIT waves + block-wide softmax.
// Grid: 1024 blocks (b = gid&7 -> batch pinned per XCD), 256 threads, 4 waves.
// Block owns 16 query rows (n0). Per iteration (128 m):
//   phase A: wave w computes S chunk m_w = it*128+w*32 (swapped QK^T, as r5),
//            chunk max -> smax[w].  barrier.
//   phase B: block max -> m_new; alpha; P = exp(S-m_new) -> pbuf[w] (bf16);
//            chunk sum -> ssum[w].  barrier.
//   phase C: l_run += sum(ssum); wave w accumulates PV for ITS channel slice
//            c in [64w, 64w+64) over ALL 128 m (reads all 4 pbuf chunks).
// acc = 4 x f32x4 = 16 regs/lane (vs 64 in r6) -> with launch_bounds(256,4)
// total regs <=128 -> 4 waves/SIMD. No split-KV merge; LDS 9.5 KB.
// All waves replicate identical m_run/l_run (deterministic from shared LDS).
// ---------------------------------------------------------------------------
__global__ __launch_bounds__(256, 4) void attn_k(
    const u16* __restrict__ qt, const u16* __restrict__ kt,
    const u16* __restrict__ vt, const float* __restrict__ xres,
    float* __restrict__ out)
{
    const int gid = blockIdx.x;
    const int b   = gid & 7;
    const int n0  = (gid >> 3) * 16;
    const int tid = threadIdx.x;
    const int w   = tid >> 6;
    const int l   = tid & 63;
    const int lx  = l & 15;
    const int lg  = l >> 4;

    __shared__ u32   pbuf[4][32][17];   // 8704 B: P bf16 (low 16b), [chunk][m-slot][n]
    __shared__ float smax[4][17];       // per-chunk row max
    __shared__ float ssum[4][17];       // per-chunk row sum

    // Q fragments (B-operand): lane holds Q[n0+lx][k = kb*32 + lg*8 + e]
    const u16* qrow = qt + ((size_t)b * N_ + n0 + lx) * C_ + lg * 8;
    bf16x8 qf[8];
    #pragma unroll
    for (int kb = 0; kb < 8; ++kb) qf[kb] = ldg8(qrow + kb * 32);

    const u16* kbase = kt + (size_t)b * N_ * C_;
    const u16* vbase = vt + (size_t)b * C_ * N_;
    const int  cb    = w * 64;          // this wave's channel slice

    f32x4 acc[4];
    #pragma unroll
    for (int ct = 0; ct < 4; ++ct) acc[ct] = (f32x4){0.f, 0.f, 0.f, 0.f};
    float mrun = -1e30f, lrun = 0.f;    // row n = lx (replicated block-wide)

    #pragma unroll 1
    for (int it = 0; it < 16; ++it) {
        const int m0 = it * 128 + w * 32;

        // ---- phase A: S^T chunk (A = K rows m, B = Q rows n) ----
        f32x4 s0 = (f32x4){0.f,0.f,0.f,0.f}, s1 = (f32x4){0.f,0.f,0.f,0.f};
        const u16* k0 = kbase + (size_t)(m0 + lx) * C_ + lg * 8;
        #pragma unroll
        for (int kb = 0; kb < 8; ++kb) {
            bf16x8 a0 = ldg8(k0 + kb * 32);            // K row m0+lx
            bf16x8 a1 = ldg8(k0 + 16 * C_ + kb * 32);  // K row m0+16+lx
            s0 = MFMA(a0, qf[kb], s0);
            s1 = MFMA(a1, qf[kb], s1);
        }
        float mx = fmaxf(fmaxf(fmaxf(s0[0], s0[1]), fmaxf(s0[2], s0[3])),
                         fmaxf(fmaxf(s1[0], s1[1]), fmaxf(s1[2], s1[3])));
        mx = fmaxf(mx, __shfl_xor(mx, 16));
        mx = fmaxf(mx, __shfl_xor(mx, 32));
        if (lg == 0) smax[w][lx] = mx;
        __syncthreads();

        // ---- phase B: block max, P, chunk sums ----
        const float gmx  = fmaxf(fmaxf(smax[0][lx], smax[1][lx]),
                                 fmaxf(smax[2][lx], smax[3][lx]));
        const float mnew  = fmaxf(mrun, gmx);
        const float alpha = __expf(mrun - mnew);
        float r = 0.f;
        #pragma unroll
        for (int j = 0; j < 4; ++j) {
            const float p0 = __expf(s0[j] - mnew);
            const float p1 = __expf(s1[j] - mnew);
            r += p0 + p1;
            pbuf[w][4*lg + j][lx]      = (u32)f2bf(p0);
            pbuf[w][16 + 4*lg + j][lx] = (u32)f2bf(p1);
        }
        r += __shfl_xor(r, 16);
        r += __shfl_xor(r, 32);
        if (lg == 0) ssum[w][lx] = r;
        __syncthreads();

        // ---- phase C: state update + PV over all 128 m, own channel slice ----
        lrun = lrun * alpha + (ssum[0][lx] + ssum[1][lx] + ssum[2][lx] + ssum[3][lx]);
        mrun = mnew;
        if (__any(alpha != 1.0f)) {
            #pragma unroll
            for (int ct = 0; ct < 4; ++ct) {
                acc[ct][0] *= alpha; acc[ct][1] *= alpha;
                acc[ct][2] *= alpha; acc[ct][3] *= alpha;
            }
        }
        #pragma unroll
        for (int msub = 0; msub < 4; ++msub) {
            bf16x8 pf;   // B-operand: P[m = it*128 + msub*32 + lg*8+e][n=lx]
            #pragma unroll
            for (int e = 0; e < 8; ++e)
                pf[e] = (short)(u16)pbuf[msub][lg*8 + e][lx];
            const int mm = it * 128 + msub * 32;
            #pragma unroll
            for (int ct = 0; ct < 4; ++ct) {
                const u16* vp = vbase + (size_t)(cb + ct*16 + lx) * N_ + mm + lg*8;
                acc[ct] = MFMA(ldg8(vp), pf, acc[ct]);
            }
        }
    }

    // ---- epilogue: /l_run + residual + store (no merge needed) ----
    const float oinv = 1.f / lrun;
    #pragma unroll
    for (int ct = 0; ct < 4; ++ct) {
        #pragma unroll
        for (int j = 0; j < 4; ++j) {
            const int c = cb + ct*16 + 4*lg + j;
            const size_t idx = ((size_t)b * C_ + c) * N_ + n0 + lx;
            out[idx] = acc[ct][j] * oinv + xres[idx];
        }
    }
}

// ---------------------------------------------------------------------------
extern "C" void kernel_launch(void* const* d_in, const int* in_sizes, int n_in,
                              void* d_out, int out_size, void* d_ws, size_t ws_size,
                              hipStream_t stream) {
    const float* x  = (const float*)d_in[0];
    const float* Wq = (const float*)d_in[1];
    const float* bq = (const float*)d_in[2];
    const float* Wk = (const float*)d_in[3];
    const float* bk = (const float*)d_in[4];
    const float* Wv = (const float*)d_in[5];
    const float* bv = (const float*)d_in[6];
    float* outp = (float*)d_out;

    const size_t plane = (size_t)B_ * C_ * N_;   // 4,194,304 elements
    u16* qt = (u16*)d_ws;        // [B][N][C] bf16, pre-scaled 1/16
    u16* kt = qt + plane;        // [B][N][C]
    u16* vt = kt + plane;        // [B][C][N]  -> total 3*plane*2 = 25,165,824 B

    dim3 g1(N_/64, C_/64, B_);
    qkv_k<<<g1, 256, 0, stream>>>(x, Wq, bq, Wk, bk, Wv, bv, qt, kt, vt);

    attn_k<<<1024, 256, 0, stream>>>(qt, kt, vt, x, outp);
}

// Round 10
// 282.820 us; speedup vs baseline: 1.4228x; 1.3548x over previous
//
#include <hip/hip_runtime.h>
#include <math.h>

#define B_ 8
#define C_ 256
#define N_ 2048

typedef __attribute__((ext_vector_type(8))) short bf16x8;
typedef __attribute__((ext_vector_type(4))) float f32x4;
typedef unsigned int u32;
typedef unsigned short u16;

#define MFMA(a, b, c) __builtin_amdgcn_mfma_f32_16x16x32_bf16(a, b, c, 0, 0, 0)

__device__ __forceinline__ u16 f2bf(float f) {            // RNE float->bf16
    u32 u = __float_as_uint(f);
    return (u16)((u + 0x7FFFu + ((u >> 16) & 1u)) >> 16);
}
__device__ __forceinline__ bf16x8 ldg8(const u16* p) {
    return *reinterpret_cast<const bf16x8*>(p);
}

// ---------------------------------------------------------------------------
// Fragment-tiled bf16 layouts (1 KB per 16x32 fragment, coalesced MFMA loads):
//   Q2[b][nt=n/16][kb=k/32][ (n%16)*32 + (k%32) ]   (pre-scaled by 1/16)
//   K2[b][mt=m/16][kb=k/32][ (m%16)*32 + (k%32) ]
//   V2[b][ci=c/16][mt2=m/32][ (c%16)*32 + (m%32) ]
// A wave reading fragment (tile, lane l: lx=l&15, lg=l>>4) at inner offset
// lx*32+lg*8 covers bytes [0,1024) disjointly -> one coalesced transaction.
// ---------------------------------------------------------------------------

// ---------------------------------------------------------------------------
// Kernel 1: fused QKV projection -> fragment-tiled bf16 planes.
// Grid (N/64, C/64, B), 256 threads, 64x64 tiles, fp32 accumulate (unchanged).
// Epilogue: stage each output through tb, emit tiled coalesced uint4 stores.
// ---------------------------------------------------------------------------
__global__ __launch_bounds__(256) void qkv_k(
    const float* __restrict__ x,
    const float* __restrict__ Wq, const float* __restrict__ bq,
    const float* __restrict__ Wk, const float* __restrict__ bk,
    const float* __restrict__ Wv, const float* __restrict__ bv,
    u16* __restrict__ qtp, u16* __restrict__ ktp, u16* __restrict__ vtp)
{
    const int b   = blockIdx.z;
    const int o0  = blockIdx.y * 64;
    const int n0  = blockIdx.x * 64;
    const int tid = threadIdx.x;
    const int tx  = tid & 15;
    const int ty  = tid >> 4;

    __shared__ float xs[16][68];
    __shared__ float wqs[16][68], wks[16][68], wvs[16][68];
    __shared__ float tb[64][68];            // output staging

    float aq[4][4] = {}, ak[4][4] = {}, av[4][4] = {};

    const float* xb = x + (size_t)b * C_ * N_;
    const int xr = tid >> 4, xc = (tid & 15) * 4;
    const int wr = tid >> 2, wc = (tid & 3) * 4;

    for (int k0 = 0; k0 < C_; k0 += 16) {
        float4 xv = *(const float4*)(xb + (size_t)(k0 + xr) * N_ + n0 + xc);
        float4 q4 = *(const float4*)(Wq + (size_t)(o0 + wr) * C_ + k0 + wc);
        float4 k4 = *(const float4*)(Wk + (size_t)(o0 + wr) * C_ + k0 + wc);
        float4 v4 = *(const float4*)(Wv + (size_t)(o0 + wr) * C_ + k0 + wc);
        __syncthreads();   // previous iteration's LDS reads done
        *(float4*)&xs[xr][xc] = xv;
        wqs[wc+0][wr] = q4.x; wqs[wc+1][wr] = q4.y; wqs[wc+2][wr] = q4.z; wqs[wc+3][wr] = q4.w;
        wks[wc+0][wr] = k4.x; wks[wc+1][wr] = k4.y; wks[wc+2][wr] = k4.z; wks[wc+3][wr] = k4.w;
        wvs[wc+0][wr] = v4.x; wvs[wc+1][wr] = v4.y; wvs[wc+2][wr] = v4.z; wvs[wc+3][wr] = v4.w;
        __syncthreads();

        #pragma unroll
        for (int k = 0; k < 16; ++k) {
            float xl[4], ql_[4], kl_[4], vl_[4];
            *(float4*)xl  = *(const float4*)&xs[k][tx*4];
            *(float4*)ql_ = *(const float4*)&wqs[k][ty*4];
            *(float4*)kl_ = *(const float4*)&wks[k][ty*4];
            *(float4*)vl_ = *(const float4*)&wvs[k][ty*4];
            #pragma unroll
            for (int i = 0; i < 4; ++i)
                #pragma unroll
                for (int j = 0; j < 4; ++j) {
                    aq[i][j] += ql_[i] * xl[j];
                    ak[i][j] += kl_[i] * xl[j];
                    av[i][j] += vl_[i] * xl[j];
                }
        }
    }

    const int blk = tid >> 5;          // 0..7 fragment sub-tile
    const int s5  = tid & 31;

    // ---- V -> V2 (stage tb[c_l][n_l], untransposed) ----
    __syncthreads();
    #pragma unroll
    for (int i = 0; i < 4; ++i) {
        const float bvv = bv[o0 + ty*4 + i];
        float4 vv; vv.x = av[i][0]+bvv; vv.y = av[i][1]+bvv;
        vv.z = av[i][2]+bvv; vv.w = av[i][3]+bvv;
        *(float4*)&tb[ty*4 + i][tx*4] = vv;
    }
    __syncthreads();
    {
        const int ci_l = blk >> 1, mt2_l = blk & 1;
        #pragma unroll
        for (int u = 0; u < 2; ++u) {
            const int u4 = u*32 + s5;
            const int lxc = u4 >> 2, lgv = u4 & 3;
            float vals[8];
            *(float4*)&vals[0] = *(const float4*)&tb[ci_l*16 + lxc][mt2_l*32 + lgv*8];
            *(float4*)&vals[4] = *(const float4*)&tb[ci_l*16 + lxc][mt2_l*32 + lgv*8 + 4];
            u32 hw[4];
            #pragma unroll
            for (int e = 0; e < 4; ++e)
                hw[e] = (u32)f2bf(vals[2*e]) | ((u32)f2bf(vals[2*e+1]) << 16);
            const size_t dst = ((size_t)((b*16 + (o0>>4) + ci_l))*64 + (n0>>5) + mt2_l)*512 + u4*8;
            *reinterpret_cast<uint4*>(vtp + dst) = make_uint4(hw[0], hw[1], hw[2], hw[3]);
        }
    }

    // ---- Q -> Q2 (stage tb[n_l][o_l] transposed, pre-scaled 1/16) ----
    __syncthreads();
    #pragma unroll
    for (int i = 0; i < 4; ++i) {
        const float bqv = bq[o0 + ty*4 + i];
        #pragma unroll
        for (int j = 0; j < 4; ++j)
            tb[tx*4 + j][ty*4 + i] = (aq[i][j] + bqv) * 0.0625f;
    }
    __syncthreads();
    {
        const int mt_l = blk >> 1, kb_l = blk & 1;
        #pragma unroll
        for (int u = 0; u < 2; ++u) {
            const int u4 = u*32 + s5;
            const int lxm = u4 >> 2, lgq = u4 & 3;
            float vals[8];
            *(float4*)&vals[0] = *(const float4*)&tb[mt_l*16 + lxm][kb_l*32 + lgq*8];
            *(float4*)&vals[4] = *(const float4*)&tb[mt_l*16 + lxm][kb_l*32 + lgq*8 + 4];
            u32 hw[4];
            #pragma unroll
            for (int e = 0; e < 4; ++e)
                hw[e] = (u32)f2bf(vals[2*e]) | ((u32)f2bf(vals[2*e+1]) << 16);
            const size_t dst = ((size_t)((b*128 + (n0>>4) + mt_l))*8 + (o0>>5) + kb_l)*512 + u4*8;
            *reinterpret_cast<uint4*>(qtp + dst) = make_uint4(hw[0], hw[1], hw[2], hw[3]);
        }
    }

    // ---- K -> K2 (stage tb[n_l][o_l] transposed) ----
    __syncthreads();
    #pragma unroll
    for (int i = 0; i < 4; ++i) {
        const float bkv = bk[o0 + ty*4 + i];
        #pragma unroll
        for (int j = 0; j < 4; ++j)
            tb[tx*4 + j][ty*4 + i] = ak[i][j] + bkv;
    }
    __syncthreads();
    {
        const int mt_l = blk >> 1, kb_l = blk & 1;
        #pragma unroll
        for (int u = 0; u < 2; ++u) {
            const int u4 = u*32 + s5;
            const int lxm = u4 >> 2, lgq = u4 & 3;
            float vals[8];
            *(float4*)&vals[0] = *(const float4*)&tb[mt_l*16 + lxm][kb_l*32 + lgq*8];
            *(float4*)&vals[4] = *(const float4*)&tb[mt_l*16 + lxm][kb_l*32 + lgq*8 + 4];
            u32 hw[4];
            #pragma unroll
            for (int e = 0; e < 4; ++e)
                hw[e] = (u32)f2bf(vals[2*e]) | ((u32)f2bf(vals[2*e+1]) << 16);
            const size_t dst = ((size_t)((b*128 + (n0>>4) + mt_l))*8 + (o0>>5) + kb_l)*512 + u4*8;
            *reinterpret_cast<uint4*>(ktp + dst) = make_uint4(hw[0], hw[1], hw[2], hw[3]);
        }
    }
}

// ---------------------------------------------------------------------------
// Kernel 2: MFMA flash attention — channel-split waves + block-wide softmax.
// IDENTICAL math/barriers to round 9; only operand addressing changed to the
// fragment-tiled layout (every ldg8 is now one coalesced 1024 B transaction).
// ---------------------------------------------------------------------------
__global__ __launch_bounds__(256, 4) void attn_k(
    const u16* __restrict__ qt, const u16* __restrict__ kt,
    const u16* __restrict__ vt, const float* __restrict__ xres,
    float* __restrict__ out)
{
    const int gid = blockIdx.x;
    const int b   = gid & 7;
    const int nt  = gid >> 3;           // n-tile index (16 rows)
    const int n0  = nt * 16;
    const int tid = threadIdx.x;
    const int w   = tid >> 6;
    const int l   = tid & 63;
    const int lx  = l & 15;
    const int lg  = l >> 4;
    const int loff = lx*32 + lg*8;      // intra-fragment lane offset

    __shared__ u32   pbuf[4][32][17];   // P bf16 (low 16b), [chunk][m-slot][n]
    __shared__ float smax[4][17];
    __shared__ float ssum[4][17];

    // Q fragments: Q2[b][nt][kb][loff]
    const u16* qbase = qt + ((size_t)(b*128 + nt) * 8) * 512 + loff;
    bf16x8 qf[8];
    #pragma unroll
    for (int kb = 0; kb < 8; ++kb) qf[kb] = ldg8(qbase + kb * 512);

    const u16* kbase = kt + (size_t)(b*128) * 8 * 512 + loff;   // K2[b][mt][kb]
    const u16* vbase = vt + (size_t)(b*16) * 64 * 512 + loff;   // V2[b][ci][mt2]
    const int  cb    = w * 64;          // this wave's channel slice

    f32x4 acc[4];
    #pragma unroll
    for (int ct = 0; ct < 4; ++ct) acc[ct] = (f32x4){0.f, 0.f, 0.f, 0.f};
    float mrun = -1e30f, lrun = 0.f;

    #pragma unroll 1
    for (int it = 0; it < 16; ++it) {
        const int mt0 = it*8 + w*2;     // m-tile (16-row) index of this chunk

        // ---- phase A: S^T chunk (A = K fragment, B = Q fragment) ----
        f32x4 s0 = (f32x4){0.f,0.f,0.f,0.f}, s1 = (f32x4){0.f,0.f,0.f,0.f};
        const u16* k0 = kbase + (size_t)(mt0*8) * 512;
        #pragma unroll
        for (int kb = 0; kb < 8; ++kb) {
            bf16x8 a0 = ldg8(k0 + kb * 512);             // K rows [16*mt0 ..]
            bf16x8 a1 = ldg8(k0 + (8 + kb) * 512);       // K rows [16*(mt0+1) ..]
            s0 = MFMA(a0, qf[kb], s0);
            s1 = MFMA(a1, qf[kb], s1);
        }
        float mx = fmaxf(fmaxf(fmaxf(s0[0], s0[1]), fmaxf(s0[2], s0[3])),
                         fmaxf(fmaxf(s1[0], s1[1]), fmaxf(s1[2], s1[3])));
        mx = fmaxf(mx, __shfl_xor(mx, 16));
        mx = fmaxf(mx, __shfl_xor(mx, 32));
        if (lg == 0) smax[w][lx] = mx;
        __syncthreads();

        // ---- phase B: block max, P, chunk sums ----
        const float gmx  = fmaxf(fmaxf(smax[0][lx], smax[1][lx]),
                                 fmaxf(smax[2][lx], smax[3][lx]));
        const float mnew  = fmaxf(mrun, gmx);
        const float alpha = __expf(mrun - mnew);
        float r = 0.f;
        #pragma unroll
        for (int j = 0; j < 4; ++j) {
            const float p0 = __expf(s0[j] - mnew);
            const float p1 = __expf(s1[j] - mnew);
            r += p0 + p1;
            pbuf[w][4*lg + j][lx]      = (u32)f2bf(p0);
            pbuf[w][16 + 4*lg + j][lx] = (u32)f2bf(p1);
        }
        r += __shfl_xor(r, 16);
        r += __shfl_xor(r, 32);
        if (lg == 0) ssum[w][lx] = r;
        __syncthreads();

        // ---- phase C: state update + PV over all 128 m, own channel slice ----
        lrun = lrun * alpha + (ssum[0][lx] + ssum[1][lx] + ssum[2][lx] + ssum[3][lx]);
        mrun = mnew;
        if (__any(alpha != 1.0f)) {
            #pragma unroll
            for (int ct = 0; ct < 4; ++ct) {
                acc[ct][0] *= alpha; acc[ct][1] *= alpha;
                acc[ct][2] *= alpha; acc[ct][3] *= alpha;
            }
        }
        #pragma unroll
        for (int msub = 0; msub < 4; ++msub) {
            bf16x8 pf;   // B-operand: P[m-slot lg*8+e][n=lx]
            #pragma unroll
            for (int e = 0; e < 8; ++e)
                pf[e] = (short)(u16)pbuf[msub][lg*8 + e][lx];
            const int mt2 = it*4 + msub;               // 32-row V tile index
            #pragma unroll
            for (int ct = 0; ct < 4; ++ct) {
                const u16* vp = vbase + (size_t)((cb>>4) + ct) * 64 * 512 + (size_t)mt2 * 512;
                acc[ct] = MFMA(ldg8(vp), pf, acc[ct]);
            }
        }
    }

    // ---- epilogue: /l_run + residual + store ----
    const float oinv = 1.f / lrun;
    #pragma unroll
    for (int ct = 0; ct < 4; ++ct) {
        #pragma unroll
        for (int j = 0; j < 4; ++j) {
            const int c = cb + ct*16 + 4*lg + j;
            const size_t idx = ((size_t)b * C_ + c) * N_ + n0 + lx;
            out[idx] = acc[ct][j] * oinv + xres[idx];
        }
    }
}

// ---------------------------------------------------------------------------
extern "C" void kernel_launch(void* const* d_in, const int* in_sizes, int n_in,
                              void* d_out, int out_size, void* d_ws, size_t ws_size,
                              hipStream_t stream) {
    const float* x  = (const float*)d_in[0];
    const float* Wq = (const float*)d_in[1];
    const float* bq = (const float*)d_in[2];
    const float* Wk = (const float*)d_in[3];
    const float* bk = (const float*)d_in[4];
    const float* Wv = (const float*)d_in[5];
    const float* bv = (const float*)d_in[6];
    float* outp = (float*)d_out;

    const size_t plane = (size_t)B_ * C_ * N_;   // 4,194,304 elements
    u16* qt = (u16*)d_ws;        // Q2 fragment-tiled, pre-scaled 1/16
    u16* kt = qt + plane;        // K2 fragment-tiled
    u16* vt = kt + plane;        // V2 fragment-tiled  (total 24 MB)

    dim3 g1(N_/64, C_/64, B_);
    qkv_k<<<g1, 256, 0, stream>>>(x, Wq, bq, Wk, bk, Wv, bv, qt, kt, vt);

    attn_k<<<1024, 256, 0, stream>>>(qt, kt, vt, x, outp);
}